// Round 5
// baseline (603.299 us; speedup 1.0000x reference)
//
#include <hip/hip_runtime.h>

// BiGRU, B=512, T=512, D=16, H=64.
// Backward direction needs only ONE cell step (ys_b[0] = GRUCell(x[:,T-1,:], 0)).
//
// Round-7: fused 2-wave kernel, K=32 split.
//  - Evidence (R4): 1-wave rec with 192 weight floats -> allocator spills
//    weights to AGPRs (VGPR_Count=112) and issues ~2x the needed VALU ops
//    (VALUBusy 40% of a 50% 2-SIMD ceiling). 4-wave R2 paid the same
//    ~1400cyc/step via exchange+redundancy. Also proj kernel + xg round-trip
//    cost ~100us of the 407 total.
//  - Fix: 2 waves/batch, 96 W_hh floats per wave (under the AGPR cliff),
//    input projection computed in-wave from wave-uniform x loads (s_load
//    broadcast, no LDS staging, no xg workspace, no second kernel).
//  - Exchange: 3 ds_write + 1 barrier + 6 ds_read (parity double-buffer),
//    both waves reduce in fixed order -> bitwise-identical h, no 2nd barrier.
//  - 512 blocks x 128 thr = 4 waves/CU = 1 per SIMD.

#define Hh 64
#define Dd 16
#define Tt 512
#define Bb 512
#define KW 32    // k-columns per wave

__device__ __forceinline__ float rcp_fast(float v) { return __builtin_amdgcn_rcpf(v); }
__device__ __forceinline__ float sigmoid_fast(float v) {
    return rcp_fast(1.0f + __expf(-v));
}
__device__ __forceinline__ float tanh_fast(float v) {
    return 1.0f - 2.0f * rcp_fast(__expf(2.0f * v) + 1.0f);
}
__device__ __forceinline__ float lane_bcast(float v, int k) {
    return __int_as_float(__builtin_amdgcn_readlane(__float_as_int(v), k));
}
__device__ __forceinline__ float dot4(float4 a, float4 b) {
    return a.x * b.x + a.y * b.y + a.z * b.z + a.w * b.w;
}

// One recurrence step. S in [0,4): parity (S&1) and all LDS offsets are
// compile-time. XB = register x-buffer (float4[4]) holding x_t for this step;
// reloaded with x[TP] (TP clamped) after consumption.
// LDS layout: parts[2][2][3][64]; buffer stride 384, wave stride 192,
// gate stride 64 floats.
#define FSTEP(S, XB, TP) do {                                                \
    /* input projection + biases (identical in both waves) */                \
    float ar = bxr + dot4(wir[0], XB[0]) + dot4(wir[1], XB[1])               \
                   + dot4(wir[2], XB[2]) + dot4(wir[3], XB[3]);              \
    float az = bxz + dot4(wiz[0], XB[0]) + dot4(wiz[1], XB[1])               \
                   + dot4(wiz[2], XB[2]) + dot4(wiz[3], XB[3]);              \
    float ax = bxn + dot4(win[0], XB[0]) + dot4(win[1], XB[1])               \
                   + dot4(win[2], XB[2]) + dot4(win[3], XB[3]);              \
    /* K-split recurrent matvec: this wave's 32 columns */                   \
    float pr = 0.f, pz = 0.f, pn = 0.f;                                      \
    _Pragma("unroll")                                                        \
    for (int kk = 0; kk < KW; ++kk) {                                        \
        const float hk = lane_bcast(h, k0 + kk);                             \
        pr += whr[kk] * hk;                                                  \
        pz += whz[kk] * hk;                                                  \
        pn += whn[kk] * hk;                                                  \
    }                                                                        \
    pw[(S & 1) * 384 +   0] = pr;                                            \
    pw[(S & 1) * 384 +  64] = pz;                                            \
    pw[(S & 1) * 384 + 128] = pn;                                            \
    /* prefetch x for step TP into XB (wave-uniform -> scalar loads) */      \
    {                                                                        \
        int tp_ = (TP);                                                      \
        if (tp_ > Tt - 1) tp_ = Tt - 1;                                      \
        const float4* xq_ = (const float4*)(xrow + (size_t)tp_ * Dd);        \
        XB[0] = xq_[0]; XB[1] = xq_[1]; XB[2] = xq_[2]; XB[3] = xq_[3];      \
    }                                                                        \
    __syncthreads();                                                         \
    /* both waves read both partials in fixed order -> identical h */        \
    const float q00 = prd[(S & 1) * 384 +   0];                              \
    const float q01 = prd[(S & 1) * 384 +  64];                              \
    const float q02 = prd[(S & 1) * 384 + 128];                              \
    const float q10 = prd[(S & 1) * 384 + 192];                              \
    const float q11 = prd[(S & 1) * 384 + 256];                              \
    const float q12 = prd[(S & 1) * 384 + 320];                              \
    ar += q00 + q10;                                                         \
    az += q01 + q11;                                                         \
    const float hn = bhn + (q02 + q12);                                      \
    const float r = sigmoid_fast(ar);                                        \
    const float z = sigmoid_fast(az);                                        \
    const float n = tanh_fast(ax + r * hn);                                  \
    h = n + z * (h - n);                                                     \
} while (0)

__global__ __launch_bounds__(128, 1)
void bigru_fused_kernel(const float* __restrict__ x,
                        const float* __restrict__ w_ih_f, const float* __restrict__ w_hh_f,
                        const float* __restrict__ b_ih_f, const float* __restrict__ b_hh_f,
                        const float* __restrict__ w_ih_b, const float* __restrict__ w_hh_b,
                        const float* __restrict__ b_ih_b, const float* __restrict__ b_hh_b,
                        const float* __restrict__ fc_w,  const float* __restrict__ fc_b,
                        float* __restrict__ out)
{
    const int tid = threadIdx.x;
    const int j   = tid & 63;            // hidden unit
    const int w   = tid >> 6;            // wave id 0..1
    const int b   = blockIdx.x;          // batch element
    const int k0  = __builtin_amdgcn_readfirstlane(w << 5);  // SGPR k-base (0 or 32)

    __shared__ __align__(16) float parts[2][2][3][Hh];   // 3 KB

    // ---- W_hh rows {j,64+j,128+j}, cols [k0,k0+32) -> 96 VGPRs ----
    float whr[KW], whz[KW], whn[KW];
    {
        const float4* r0 = (const float4*)(w_hh_f + (size_t)j            * Hh + k0);
        const float4* r1 = (const float4*)(w_hh_f + (size_t)(Hh + j)     * Hh + k0);
        const float4* r2 = (const float4*)(w_hh_f + (size_t)(2 * Hh + j) * Hh + k0);
#pragma unroll
        for (int q = 0; q < KW / 4; ++q) {
            float4 a = r0[q]; whr[4*q] = a.x; whr[4*q+1] = a.y; whr[4*q+2] = a.z; whr[4*q+3] = a.w;
            float4 c = r1[q]; whz[4*q] = c.x; whz[4*q+1] = c.y; whz[4*q+2] = c.z; whz[4*q+3] = c.w;
            float4 e = r2[q]; whn[4*q] = e.x; whn[4*q+1] = e.y; whn[4*q+2] = e.z; whn[4*q+3] = e.w;
        }
    }
    // ---- W_ih rows {j,64+j,128+j} (16 cols) -> 48 VGPRs ----
    float4 wir[4], wiz[4], win[4];
    {
        const float4* p0 = (const float4*)(w_ih_f + (size_t)j            * Dd);
        const float4* p1 = (const float4*)(w_ih_f + (size_t)(Hh + j)     * Dd);
        const float4* p2 = (const float4*)(w_ih_f + (size_t)(2 * Hh + j) * Dd);
#pragma unroll
        for (int q = 0; q < 4; ++q) { wir[q] = p0[q]; wiz[q] = p1[q]; win[q] = p2[q]; }
    }
    const float bxr = b_ih_f[j]          + b_hh_f[j];
    const float bxz = b_ih_f[Hh + j]     + b_hh_f[Hh + j];
    const float bxn = b_ih_f[2 * Hh + j];
    const float bhn = b_hh_f[2 * Hh + j];

    // per-lane LDS bases
    float*       pw  = &parts[0][w][0][j];   // this wave's write base
    const float* prd = &parts[0][0][0][j];   // read base (both waves, fixed order)

    const float* xrow = x + (size_t)b * Tt * Dd;

    // x register buffers: even/odd steps, 2-step prefetch distance.
    // Addresses are wave-uniform -> compiler emits scalar (s_load) broadcasts.
    float4 xE[4], xO[4];
    {
        const float4* q0 = (const float4*)(xrow);
        const float4* q1 = (const float4*)(xrow + Dd);
        xE[0] = q0[0]; xE[1] = q0[1]; xE[2] = q0[2]; xE[3] = q0[3];
        xO[0] = q1[0]; xO[1] = q1[1]; xO[2] = q1[2]; xO[3] = q1[3];
    }

    float h = 0.0f;

    for (int t = 0; t < Tt; t += 4) {
        FSTEP(0, xE, t + 2);
        FSTEP(1, xO, t + 3);
        FSTEP(2, xE, t + 4);
        FSTEP(3, xO, t + 5);
    }

    // ---- tail: backward single cell step + FC, wave 0 only ----
    if (w == 0) {
        float ar   = b_ih_b[j]          + b_hh_b[j];
        float az   = b_ih_b[Hh + j]     + b_hh_b[Hh + j];
        float axn  = b_ih_b[2 * Hh + j];
        const float bhnb = b_hh_b[2 * Hh + j];
        {
            const float4* xl = (const float4*)(xrow + (size_t)(Tt - 1) * Dd);
            float4 xv0 = xl[0], xv1 = xl[1], xv2 = xl[2], xv3 = xl[3];
            const float4* q0 = (const float4*)(w_ih_b + (size_t)j            * Dd);
            const float4* q1 = (const float4*)(w_ih_b + (size_t)(Hh + j)     * Dd);
            const float4* q2 = (const float4*)(w_ih_b + (size_t)(2 * Hh + j) * Dd);
            ar  += dot4(q0[0], xv0) + dot4(q0[1], xv1) + dot4(q0[2], xv2) + dot4(q0[3], xv3);
            az  += dot4(q1[0], xv0) + dot4(q1[1], xv1) + dot4(q1[2], xv2) + dot4(q1[3], xv3);
            axn += dot4(q2[0], xv0) + dot4(q2[1], xv1) + dot4(q2[2], xv2) + dot4(q2[3], xv3);
        }
        const float rb = sigmoid_fast(ar);
        const float zb = sigmoid_fast(az);
        const float nb = tanh_fast(axn + rb * bhnb);
        const float hb = (1.0f - zb) * nb;   // h0 = 0

        float v = fc_w[j] * h + fc_w[Hh + j] * hb;
#pragma unroll
        for (int off = 32; off > 0; off >>= 1)
            v += __shfl_xor(v, off, 64);
        if (j == 0) out[b] = v + fc_b[0];
    }
}

extern "C" void kernel_launch(void* const* d_in, const int* in_sizes, int n_in,
                              void* d_out, int out_size, void* d_ws, size_t ws_size,
                              hipStream_t stream) {
    const float* x      = (const float*)d_in[0];
    const float* w_ih_f = (const float*)d_in[1];
    const float* w_hh_f = (const float*)d_in[2];
    const float* b_ih_f = (const float*)d_in[3];
    const float* b_hh_f = (const float*)d_in[4];
    const float* w_ih_b = (const float*)d_in[5];
    const float* w_hh_b = (const float*)d_in[6];
    const float* b_ih_b = (const float*)d_in[7];
    const float* b_hh_b = (const float*)d_in[8];
    const float* fc_w   = (const float*)d_in[9];
    const float* fc_b   = (const float*)d_in[10];

    bigru_fused_kernel<<<dim3(Bb), dim3(128), 0, stream>>>(
        x, w_ih_f, w_hh_f, b_ih_f, b_hh_f,
        w_ih_b, w_hh_b, b_ih_b, b_hh_b, fc_w, fc_b,
        (float*)d_out);
}

// Round 6
// 498.811 us; speedup vs baseline: 1.2095x; 1.2095x over previous
//
#include <hip/hip_runtime.h>

// BiGRU, B=512, T=512, D=16, H=64.
// Backward direction needs only ONE cell step (ys_b[0] = GRUCell(x[:,T-1,:], 0)).
//
// Round-8: single kernel, ONE WAVE PER BATCH, two block-local phases.
//  Evidence: R4's rec (1 wave, no sync) = best per-chain cost (1425 cyc/step,
//  issue=570=hand count, rest stalls); its loss was the separate proj kernel
//  + dispatch gap (~103us). R5 (2-wave K32 exchange) regressed: 1 wave/SIMD
//  cannot hide barrier latency and weights were demoted out of arch VGPRs.
//
//  Phase A (per wave): project OWN batch's x into xg workspace (block-local
//    dependency only -> no grid sync, no second dispatch). W_ih regs die here.
//  Phase B: R4-rec + stall fixes:
//    - readlanes grouped 8-ahead into uniform temps (SGPRs): no FMA issues
//      immediately after its readlane -> VALU->SGPR->VALU hazard hidden.
//    - __launch_bounds__(64,2): 256-reg unified budget -> W_hh (192 floats)
//      must be arch-VGPR resident (no AGPR/demotion copy traffic).
//  Fallback: verified round-2 monolithic kernel if ws too small.

#define Hh 64
#define Dd 16
#define Tt 512
#define Bb 512
#define G3 192   // 3*H
#define CH 64    // fallback: timesteps per LDS chunk
#define NW 4     // fallback: waves per block
#define KW 16    // fallback: k-columns per wave

__device__ __forceinline__ float rcp_fast(float v) { return __builtin_amdgcn_rcpf(v); }
__device__ __forceinline__ float sigmoid_fast(float v) {
    return rcp_fast(1.0f + __expf(-v));
}
__device__ __forceinline__ float tanh_fast(float v) {
    return 1.0f - 2.0f * rcp_fast(__expf(2.0f * v) + 1.0f);
}
__device__ __forceinline__ float lane_bcast(float v, int k) {
    return __int_as_float(__builtin_amdgcn_readlane(__float_as_int(v), k));
}
__device__ __forceinline__ float dot4(float4 a, float4 b) {
    return a.x * b.x + a.y * b.y + a.z * b.z + a.w * b.w;
}

// ---------------------------------------------------------------------------
// Main kernel: grid (Bb), block 64 = one wave per batch element.
// ---------------------------------------------------------------------------

// 8 grouped broadcasts then 24 FMAs: readlane->use distance >= 8 instrs.
#define RGRP(G)                                                              \
    {                                                                        \
        const float g0 = lane_bcast(h, 8*(G)+0);                             \
        const float g1 = lane_bcast(h, 8*(G)+1);                             \
        const float g2 = lane_bcast(h, 8*(G)+2);                             \
        const float g3 = lane_bcast(h, 8*(G)+3);                             \
        const float g4 = lane_bcast(h, 8*(G)+4);                             \
        const float g5 = lane_bcast(h, 8*(G)+5);                             \
        const float g6 = lane_bcast(h, 8*(G)+6);                             \
        const float g7 = lane_bcast(h, 8*(G)+7);                             \
        sr += whr[8*(G)+0]*g0; sz += whz[8*(G)+0]*g0; sn += whn[8*(G)+0]*g0; \
        sr += whr[8*(G)+1]*g1; sz += whz[8*(G)+1]*g1; sn += whn[8*(G)+1]*g1; \
        sr += whr[8*(G)+2]*g2; sz += whz[8*(G)+2]*g2; sn += whn[8*(G)+2]*g2; \
        sr += whr[8*(G)+3]*g3; sz += whz[8*(G)+3]*g3; sn += whn[8*(G)+3]*g3; \
        sr += whr[8*(G)+4]*g4; sz += whz[8*(G)+4]*g4; sn += whn[8*(G)+4]*g4; \
        sr += whr[8*(G)+5]*g5; sz += whz[8*(G)+5]*g5; sn += whn[8*(G)+5]*g5; \
        sr += whr[8*(G)+6]*g6; sz += whz[8*(G)+6]*g6; sn += whn[8*(G)+6]*g6; \
        sr += whr[8*(G)+7]*g7; sz += whz[8*(G)+7]*g7; sn += whn[8*(G)+7]*g7; \
    }

// One step: matvec (grouped), prefetch xg row TP into (AR,AZ,AN), gates.
#define RSTEP(XR, XZ, XN, AR, AZ, AN, TP) do {                               \
    float sr = (XR), sz = (XZ), sn = bhn;                                    \
    RGRP(0) RGRP(1) RGRP(2) RGRP(3)                                          \
    RGRP(4) RGRP(5) RGRP(6) RGRP(7)                                          \
    {                                                                        \
        int tp_ = (TP);                                                      \
        if (tp_ > Tt - 1) tp_ = Tt - 1;                                      \
        const float* pf_ = xgb + (size_t)tp_ * G3;                           \
        AR = pf_[j]; AZ = pf_[Hh + j]; AN = pf_[2 * Hh + j];                 \
    }                                                                        \
    const float r = sigmoid_fast(sr);                                        \
    const float z = sigmoid_fast(sz);                                        \
    const float n = tanh_fast((XN) + r * sn);                                \
    h = n + z * (h - n);                                                     \
} while (0)

__global__ __launch_bounds__(64, 2)
void bigru_onewave_kernel(const float* __restrict__ x,
                          const float* __restrict__ w_ih_f, const float* __restrict__ w_hh_f,
                          const float* __restrict__ b_ih_f, const float* __restrict__ b_hh_f,
                          const float* __restrict__ w_ih_b, const float* __restrict__ w_hh_b,
                          const float* __restrict__ b_ih_b, const float* __restrict__ b_hh_b,
                          const float* __restrict__ fc_w,  const float* __restrict__ fc_b,
                          float* __restrict__ xg,          // workspace [Bb][Tt][G3]
                          float* __restrict__ out)
{
    const int j = threadIdx.x;   // hidden unit 0..63
    const int b = blockIdx.x;    // batch element

    const float* xrow = x + (size_t)b * Tt * Dd;
    float* xgb = xg + (size_t)b * Tt * G3;

    // ======================= Phase A: input projection ======================
    // W_ih rows {j,64+j,128+j} (48 regs) -- DEAD after this phase.
    {
        float4 wir[4], wiz[4], win[4];
        {
            const float4* p0 = (const float4*)(w_ih_f + (size_t)j            * Dd);
            const float4* p1 = (const float4*)(w_ih_f + (size_t)(Hh + j)     * Dd);
            const float4* p2 = (const float4*)(w_ih_f + (size_t)(2 * Hh + j) * Dd);
#pragma unroll
            for (int q = 0; q < 4; ++q) { wir[q] = p0[q]; wiz[q] = p1[q]; win[q] = p2[q]; }
        }
        const float bxr = b_ih_f[j]          + b_hh_f[j];
        const float bxz = b_ih_f[Hh + j]     + b_hh_f[Hh + j];
        const float bxn = b_ih_f[2 * Hh + j];   // b_hh_n enters inside r* term

#define LOADX(BUF, T) {                                                      \
            const float4* p_ = (const float4*)(xrow + (size_t)(T) * Dd);     \
            BUF[0] = p_[0]; BUF[1] = p_[1]; BUF[2] = p_[2]; BUF[3] = p_[3];  \
        }
#define PROJSTORE(BUF, T) {                                                  \
            float ar_ = bxr + dot4(wir[0], BUF[0]) + dot4(wir[1], BUF[1])    \
                            + dot4(wir[2], BUF[2]) + dot4(wir[3], BUF[3]);   \
            float az_ = bxz + dot4(wiz[0], BUF[0]) + dot4(wiz[1], BUF[1])    \
                            + dot4(wiz[2], BUF[2]) + dot4(wiz[3], BUF[3]);   \
            float an_ = bxn + dot4(win[0], BUF[0]) + dot4(win[1], BUF[1])    \
                            + dot4(win[2], BUF[2]) + dot4(win[3], BUF[3]);   \
            float* o_ = xgb + (size_t)(T) * G3;                              \
            o_[j] = ar_; o_[Hh + j] = az_; o_[2 * Hh + j] = an_;             \
        }
        float4 xa[4], xb[4];
        LOADX(xa, 0);
        for (int t = 0; t < Tt; t += 2) {
            LOADX(xb, t + 1);
            PROJSTORE(xa, t);
            const int tn = (t + 2 < Tt) ? (t + 2) : (Tt - 1);  // clamped (dead at tail)
            LOADX(xa, tn);
            PROJSTORE(xb, t + 1);
        }
#undef LOADX
#undef PROJSTORE
    }
    // drain stores before reading them back (same wave, global round-trip)
    asm volatile("s_waitcnt vmcnt(0)" ::: "memory");

    // ========================= Phase B: recurrence ==========================
    // W_hh rows {j,64+j,128+j}: 192 regs (arch-VGPR under the 256 budget).
    float whr[Hh], whz[Hh], whn[Hh];
    {
        const float4* r0 = (const float4*)(w_hh_f + (size_t)j            * Hh);
        const float4* r1 = (const float4*)(w_hh_f + (size_t)(Hh + j)     * Hh);
        const float4* r2 = (const float4*)(w_hh_f + (size_t)(2 * Hh + j) * Hh);
#pragma unroll
        for (int q = 0; q < Hh / 4; ++q) {
            float4 a = r0[q]; whr[4*q] = a.x; whr[4*q+1] = a.y; whr[4*q+2] = a.z; whr[4*q+3] = a.w;
            float4 c = r1[q]; whz[4*q] = c.x; whz[4*q+1] = c.y; whz[4*q+2] = c.z; whz[4*q+3] = c.w;
            float4 e = r2[q]; whn[4*q] = e.x; whn[4*q+1] = e.y; whn[4*q+2] = e.z; whn[4*q+3] = e.w;
        }
    }
    const float bhn = b_hh_f[2 * Hh + j];

    // 2-deep E/O register prefetch of per-step projections.
    float arE = xgb[j],      azE = xgb[Hh + j],      anE = xgb[2 * Hh + j];
    float arO = xgb[G3 + j], azO = xgb[G3 + Hh + j], anO = xgb[G3 + 2 * Hh + j];

    float h = 0.0f;
    for (int t = 0; t < Tt; t += 2) {
        { const float xr = arE, xz = azE, xn = anE; RSTEP(xr, xz, xn, arE, azE, anE, t + 2); }
        { const float xr = arO, xz = azO, xn = anO; RSTEP(xr, xz, xn, arO, azO, anO, t + 3); }
    }

    // ---- tail: backward single cell step + FC ----
    float ar   = b_ih_b[j]          + b_hh_b[j];
    float az   = b_ih_b[Hh + j]     + b_hh_b[Hh + j];
    float axn  = b_ih_b[2 * Hh + j];
    const float bhnb = b_hh_b[2 * Hh + j];
    {
        const float4* xl = (const float4*)(xrow + (size_t)(Tt - 1) * Dd);
        float4 xv0 = xl[0], xv1 = xl[1], xv2 = xl[2], xv3 = xl[3];
        const float4* q0 = (const float4*)(w_ih_b + (size_t)j            * Dd);
        const float4* q1 = (const float4*)(w_ih_b + (size_t)(Hh + j)     * Dd);
        const float4* q2 = (const float4*)(w_ih_b + (size_t)(2 * Hh + j) * Dd);
        ar  += dot4(q0[0], xv0) + dot4(q0[1], xv1) + dot4(q0[2], xv2) + dot4(q0[3], xv3);
        az  += dot4(q1[0], xv0) + dot4(q1[1], xv1) + dot4(q1[2], xv2) + dot4(q1[3], xv3);
        axn += dot4(q2[0], xv0) + dot4(q2[1], xv1) + dot4(q2[2], xv2) + dot4(q2[3], xv3);
    }
    const float rb = sigmoid_fast(ar);
    const float zb = sigmoid_fast(az);
    const float nb = tanh_fast(axn + rb * bhnb);
    const float hb = (1.0f - zb) * nb;   // h0 = 0

    float v = fc_w[j] * h + fc_w[Hh + j] * hb;
#pragma unroll
    for (int off = 32; off > 0; off >>= 1)
        v += __shfl_xor(v, off, 64);
    if (j == 0) out[b] = v + fc_b[0];
}

// ---------------------------------------------------------------------------
// Fallback: verified round-2 monolithic kernel (318 us), used if ws too small.
// ---------------------------------------------------------------------------
#define GSTEP(S, PF) do {                                                    \
    const float xr = xr_n, xz = xz_n, xnv = xn_n;                            \
    float pr0 = 0.f, pr1 = 0.f, pz0 = 0.f, pz1 = 0.f, pn0 = 0.f, pn1 = 0.f; \
    _Pragma("unroll")                                                        \
    for (int kk = 0; kk < 8; ++kk) {                                         \
        const float ha = lane_bcast(h, k0 + kk);                             \
        const float hb = lane_bcast(h, k0 + kk + 8);                         \
        pr0 += wr[kk] * ha;   pr1 += wr[kk + 8] * hb;                        \
        pz0 += wz[kk] * ha;   pz1 += wz[kk + 8] * hb;                        \
        pn0 += wn[kk] * ha;   pn1 += wn[kk + 8] * hb;                        \
    }                                                                        \
    pw[((S)&1) * 768 +   0] = pr0 + pr1;                                     \
    pw[((S)&1) * 768 +  64] = pz0 + pz1;                                     \
    pw[((S)&1) * 768 + 128] = pn0 + pn1;                                     \
    xr_n = xgp[(PF) * Hh];                                                   \
    xz_n = xgp[CH * Hh + (PF) * Hh];                                         \
    xn_n = xgp[2 * CH * Hh + (PF) * Hh];                                     \
    __syncthreads();                                                         \
    const float q00 = prd[((S)&1) * 768 +   0];                              \
    const float q01 = prd[((S)&1) * 768 +  64];                              \
    const float q02 = prd[((S)&1) * 768 + 128];                              \
    const float q10 = prd[((S)&1) * 768 + 192];                              \
    const float q11 = prd[((S)&1) * 768 + 256];                              \
    const float q12 = prd[((S)&1) * 768 + 320];                              \
    const float q20 = prd[((S)&1) * 768 + 384];                              \
    const float q21 = prd[((S)&1) * 768 + 448];                              \
    const float q22 = prd[((S)&1) * 768 + 512];                              \
    const float q30 = prd[((S)&1) * 768 + 576];                              \
    const float q31 = prd[((S)&1) * 768 + 640];                              \
    const float q32 = prd[((S)&1) * 768 + 704];                              \
    const float ar = xr  + ((q00 + q10) + (q20 + q30));                      \
    const float az = xz  + ((q01 + q11) + (q21 + q31));                      \
    const float an = bhn + ((q02 + q12) + (q22 + q32));                      \
    const float r = sigmoid_fast(ar);                                        \
    const float z = sigmoid_fast(az);                                        \
    const float n = tanh_fast(xnv + r * an);                                 \
    h = n + z * (h - n);                                                     \
} while (0)

__global__ __launch_bounds__(256, 2)
void bigru_fused_kernel(const float* __restrict__ x,
                        const float* __restrict__ w_ih_f, const float* __restrict__ w_hh_f,
                        const float* __restrict__ b_ih_f, const float* __restrict__ b_hh_f,
                        const float* __restrict__ w_ih_b, const float* __restrict__ w_hh_b,
                        const float* __restrict__ b_ih_b, const float* __restrict__ b_hh_b,
                        const float* __restrict__ fc_w,  const float* __restrict__ fc_b,
                        float* __restrict__ out)
{
    const int tid = threadIdx.x;
    const int j   = tid & 63;
    const int w   = tid >> 6;
    const int b   = blockIdx.x;
    const int k0  = __builtin_amdgcn_readfirstlane(w << 4);

    __shared__ __align__(16) float xbuf[CH * Dd];
    __shared__ __align__(16) float xg[3][CH][Hh];
    __shared__ __align__(16) float parts[2][NW][3][Hh];

    float wr[KW], wz[KW], wn[KW];
    {
        const float4* r0 = (const float4*)(w_hh_f + (size_t)j            * Hh + k0);
        const float4* r1 = (const float4*)(w_hh_f + (size_t)(Hh + j)     * Hh + k0);
        const float4* r2 = (const float4*)(w_hh_f + (size_t)(2 * Hh + j) * Hh + k0);
#pragma unroll
        for (int q = 0; q < KW / 4; ++q) {
            float4 a = r0[q]; wr[4*q] = a.x; wr[4*q+1] = a.y; wr[4*q+2] = a.z; wr[4*q+3] = a.w;
            float4 c = r1[q]; wz[4*q] = c.x; wz[4*q+1] = c.y; wz[4*q+2] = c.z; wz[4*q+3] = c.w;
            float4 e = r2[q]; wn[4*q] = e.x; wn[4*q+1] = e.y; wn[4*q+2] = e.z; wn[4*q+3] = e.w;
        }
    }
    float4 wir[4], wiz[4], win[4];
    {
        const float4* p0 = (const float4*)(w_ih_f + (size_t)j            * Dd);
        const float4* p1 = (const float4*)(w_ih_f + (size_t)(Hh + j)     * Dd);
        const float4* p2 = (const float4*)(w_ih_f + (size_t)(2 * Hh + j) * Dd);
#pragma unroll
        for (int q = 0; q < 4; ++q) { wir[q] = p0[q]; wiz[q] = p1[q]; win[q] = p2[q]; }
    }
    const float bxr = b_ih_f[j]          + b_hh_f[j];
    const float bxz = b_ih_f[Hh + j]     + b_hh_f[Hh + j];
    const float bxn = b_ih_f[2 * Hh + j];
    const float bhn = b_hh_f[2 * Hh + j];

    float*       pw  = &parts[0][w][0][j];
    const float* prd = &parts[0][0][0][j];

    float h = 0.0f;
    const float* xrow = x + (size_t)b * Tt * Dd;

    for (int tc = 0; tc < Tt / CH; ++tc) {
        __syncthreads();
        ((float4*)xbuf)[tid] = ((const float4*)(xrow + (size_t)tc * CH * Dd))[tid];
        __syncthreads();

#pragma unroll 4
        for (int tt2 = 0; tt2 < KW; ++tt2) {
            const int tt = (w << 4) + tt2;
            const float4* x4 = (const float4*)(xbuf + tt * Dd);
            float4 xv0 = x4[0], xv1 = x4[1], xv2 = x4[2], xv3 = x4[3];
            float ar = bxr + dot4(wir[0], xv0) + dot4(wir[1], xv1) + dot4(wir[2], xv2) + dot4(wir[3], xv3);
            float az = bxz + dot4(wiz[0], xv0) + dot4(wiz[1], xv1) + dot4(wiz[2], xv2) + dot4(wiz[3], xv3);
            float an = bxn + dot4(win[0], xv0) + dot4(win[1], xv1) + dot4(win[2], xv2) + dot4(win[3], xv3);
            xg[0][tt][j] = ar;
            xg[1][tt][j] = az;
            xg[2][tt][j] = an;
        }
        __syncthreads();

        const float* xgp = &xg[0][0][j];
        float xr_n = xgp[0];
        float xz_n = xgp[CH * Hh];
        float xn_n = xgp[2 * CH * Hh];

        for (int tt = 0; tt < CH; tt += 8) {
            if (tt < CH - 8) {
                GSTEP(0, 1); GSTEP(1, 2); GSTEP(2, 3); GSTEP(3, 4);
                GSTEP(4, 5); GSTEP(5, 6); GSTEP(6, 7); GSTEP(7, 8);
            } else {
                GSTEP(0, 1); GSTEP(1, 2); GSTEP(2, 3); GSTEP(3, 4);
                GSTEP(4, 5); GSTEP(5, 6); GSTEP(6, 7); GSTEP(7, 7);
            }
            xgp += 8 * Hh;
        }
    }

    if (w == 0) {
        float ar   = b_ih_b[j]          + b_hh_b[j];
        float az   = b_ih_b[Hh + j]     + b_hh_b[Hh + j];
        float axn  = b_ih_b[2 * Hh + j];
        float bhnb = b_hh_b[2 * Hh + j];
        {
            const float4* xl = (const float4*)(xbuf + 63 * Dd);
            const float4* q0 = (const float4*)(w_ih_b + (size_t)j            * Dd);
            const float4* q1 = (const float4*)(w_ih_b + (size_t)(Hh + j)     * Dd);
            const float4* q2 = (const float4*)(w_ih_b + (size_t)(2 * Hh + j) * Dd);
#pragma unroll
            for (int q = 0; q < 4; ++q) {
                float4 xv = xl[q];
                float4 a = q0[q], c = q1[q], e = q2[q];
                ar  += a.x * xv.x + a.y * xv.y + a.z * xv.z + a.w * xv.w;
                az  += c.x * xv.x + c.y * xv.y + c.z * xv.z + c.w * xv.w;
                axn += e.x * xv.x + e.y * xv.y + e.z * xv.z + e.w * xv.w;
            }
        }
        float rb = sigmoid_fast(ar);
        float zb = sigmoid_fast(az);
        float nb2 = tanh_fast(axn + rb * bhnb);
        float hb = (1.0f - zb) * nb2;

        float v = fc_w[j] * h + fc_w[Hh + j] * hb;
#pragma unroll
        for (int off = 32; off > 0; off >>= 1)
            v += __shfl_xor(v, off, 64);
        if (j == 0) out[b] = v + fc_b[0];
    }
}

extern "C" void kernel_launch(void* const* d_in, const int* in_sizes, int n_in,
                              void* d_out, int out_size, void* d_ws, size_t ws_size,
                              hipStream_t stream) {
    const float* x      = (const float*)d_in[0];
    const float* w_ih_f = (const float*)d_in[1];
    const float* w_hh_f = (const float*)d_in[2];
    const float* b_ih_f = (const float*)d_in[3];
    const float* b_hh_f = (const float*)d_in[4];
    const float* w_ih_b = (const float*)d_in[5];
    const float* w_hh_b = (const float*)d_in[6];
    const float* b_ih_b = (const float*)d_in[7];
    const float* b_hh_b = (const float*)d_in[8];
    const float* fc_w   = (const float*)d_in[9];
    const float* fc_b   = (const float*)d_in[10];

    const size_t need = (size_t)Bb * Tt * G3 * sizeof(float);   // 201,326,592 B
    if (d_ws != nullptr && ws_size >= need) {
        bigru_onewave_kernel<<<dim3(Bb), dim3(64), 0, stream>>>(
            x, w_ih_f, w_hh_f, b_ih_f, b_hh_f,
            w_ih_b, w_hh_b, b_ih_b, b_hh_b, fc_w, fc_b,
            (float*)d_ws, (float*)d_out);
    } else {
        bigru_fused_kernel<<<dim3(Bb), dim3(NW * 64), 0, stream>>>(
            x, w_ih_f, w_hh_f, b_ih_f, b_hh_f,
            w_ih_b, w_hh_b, b_ih_b, b_hh_b, fc_w, fc_b,
            (float*)d_out);
    }
}

// Round 7
// 363.545 us; speedup vs baseline: 1.6595x; 1.3721x over previous
//
#include <hip/hip_runtime.h>

// BiGRU, B=512, T=512, D=16, H=64.
// Backward direction needs only ONE cell step (ys_b[0] = GRUCell(x[:,T-1,:], 0)).
//
// Round-9: producer/consumer wave specialization, ALL traffic in LDS.
//  Evidence: R6 showed the xg global round-trip (FETCH 115MB + WRITE 196MB at
//  ~670GB/s) IS the kernel time; R4-rec's 304us = 98MB at 331GB/s latency-bound.
//  R2 (318us) has the right memory shape (FETCH 8.5MB) but pays per-step
//  barrier + 4x redundant gates.
//  This kernel: block = 4 waves. Wave (blockIdx&3) = CONSUMER: full W_hh in
//  registers (disjoint branch -> W_ih never co-live), runs the recurrence
//  alone: 192 FMA + 64 grouped readlane + 3 ds_read + gates per step. No
//  per-step sync. Other 3 waves = PRODUCERS: input projections chunk-wise
//  (CH=32) into double-buffered LDS xg; one s_barrier per chunk (16 total).
//  512 blocks x 256 thr = 2 blocks/CU, 48KB LDS/block.

#define Hh 64
#define Dd 16
#define Tt 512
#define Bb 512
#define CH 32
#define NC (Tt / CH)        // 16 chunks
#define PLANE (CH * Hh)     // 2048 floats per gate plane
#define BUFSZ (3 * PLANE)   // 6144 floats per buffer

__device__ __forceinline__ float rcp_fast(float v) { return __builtin_amdgcn_rcpf(v); }
__device__ __forceinline__ float sigmoid_fast(float v) {
    return rcp_fast(1.0f + __expf(-v));
}
__device__ __forceinline__ float tanh_fast(float v) {
    return 1.0f - 2.0f * rcp_fast(__expf(2.0f * v) + 1.0f);
}
__device__ __forceinline__ float lane_bcast(float v, int k) {
    return __int_as_float(__builtin_amdgcn_readlane(__float_as_int(v), k));
}
__device__ __forceinline__ float dot4(float4 a, float4 b) {
    return a.x * b.x + a.y * b.y + a.z * b.z + a.w * b.w;
}
// waitcnt + barrier in one asm: orders LDS ops across waves; "memory" clobber
// stops the compiler moving LDS accesses across it. Branch cond is
// wave-uniform, and both branches execute exactly NC barriers.
__device__ __forceinline__ void lds_barrier() {
    asm volatile("s_waitcnt lgkmcnt(0)\n\ts_barrier" ::: "memory");
}

// 8 broadcasts then 24 FMAs: readlane->use distance kept long.
#define RGRP(G)                                                              \
    {                                                                        \
        const float g0 = lane_bcast(h, 8*(G)+0);                             \
        const float g1 = lane_bcast(h, 8*(G)+1);                             \
        const float g2 = lane_bcast(h, 8*(G)+2);                             \
        const float g3 = lane_bcast(h, 8*(G)+3);                             \
        const float g4 = lane_bcast(h, 8*(G)+4);                             \
        const float g5 = lane_bcast(h, 8*(G)+5);                             \
        const float g6 = lane_bcast(h, 8*(G)+6);                             \
        const float g7 = lane_bcast(h, 8*(G)+7);                             \
        sr += whr[8*(G)+0]*g0; sz += whz[8*(G)+0]*g0; sn += whn[8*(G)+0]*g0; \
        sr += whr[8*(G)+1]*g1; sz += whz[8*(G)+1]*g1; sn += whn[8*(G)+1]*g1; \
        sr += whr[8*(G)+2]*g2; sz += whz[8*(G)+2]*g2; sn += whn[8*(G)+2]*g2; \
        sr += whr[8*(G)+3]*g3; sz += whz[8*(G)+3]*g3; sn += whn[8*(G)+3]*g3; \
        sr += whr[8*(G)+4]*g4; sz += whz[8*(G)+4]*g4; sn += whn[8*(G)+4]*g4; \
        sr += whr[8*(G)+5]*g5; sz += whz[8*(G)+5]*g5; sn += whn[8*(G)+5]*g5; \
        sr += whr[8*(G)+6]*g6; sz += whz[8*(G)+6]*g6; sn += whn[8*(G)+6]*g6; \
        sr += whr[8*(G)+7]*g7; sz += whz[8*(G)+7]*g7; sn += whn[8*(G)+7]*g7; \
    }

__global__ __launch_bounds__(256, 2)
void bigru_pc_kernel(const float* __restrict__ x,
                     const float* __restrict__ w_ih_f, const float* __restrict__ w_hh_f,
                     const float* __restrict__ b_ih_f, const float* __restrict__ b_hh_f,
                     const float* __restrict__ w_ih_b, const float* __restrict__ w_hh_b,
                     const float* __restrict__ b_ih_b, const float* __restrict__ b_hh_b,
                     const float* __restrict__ fc_w,  const float* __restrict__ fc_b,
                     float* __restrict__ out)
{
    const int tid  = threadIdx.x;
    const int j    = tid & 63;          // hidden unit
    const int w    = tid >> 6;          // wave 0..3
    const int b    = blockIdx.x;        // batch element
    const int cons = b & 3;             // consumer wave id (spread across SIMDs)

    __shared__ __align__(16) float xgs[2 * BUFSZ];   // 48 KB double-buffered xg

    const float* xrow = x + (size_t)b * Tt * Dd;

    if (w == cons) {
        // ===================== CONSUMER: the recurrence =====================
        // Full W_hh rows {j,64+j,128+j}: 192 VGPRs. W_ih never live here.
        float whr[Hh], whz[Hh], whn[Hh];
        {
            const float4* r0 = (const float4*)(w_hh_f + (size_t)j            * Hh);
            const float4* r1 = (const float4*)(w_hh_f + (size_t)(Hh + j)     * Hh);
            const float4* r2 = (const float4*)(w_hh_f + (size_t)(2 * Hh + j) * Hh);
#pragma unroll
            for (int q = 0; q < Hh / 4; ++q) {
                float4 a = r0[q]; whr[4*q] = a.x; whr[4*q+1] = a.y; whr[4*q+2] = a.z; whr[4*q+3] = a.w;
                float4 c = r1[q]; whz[4*q] = c.x; whz[4*q+1] = c.y; whz[4*q+2] = c.z; whz[4*q+3] = c.w;
                float4 e = r2[q]; whn[4*q] = e.x; whn[4*q+1] = e.y; whn[4*q+2] = e.z; whn[4*q+3] = e.w;
            }
        }
        const float bhnr = b_hh_f[2 * Hh + j];
        float h = 0.0f;

        for (int c = 0; c < NC; ++c) {
            lds_barrier();                       // chunk c is ready in buf[c&1]
            const float* base = xgs + (c & 1) * BUFSZ + j;
            float par = base[0];
            float paz = base[PLANE];
            float pan = base[2 * PLANE];
#pragma unroll 4
            for (int t = 0; t < CH; ++t) {
                float nar = 0.f, naz = 0.f, nan = 0.f;
                if (t < CH - 1) {                // prefetch next step (latency
                    const float* p = base + (t + 1) * Hh;   // hidden under FMAs)
                    nar = p[0]; naz = p[PLANE]; nan = p[2 * PLANE];
                }
                float sr = 0.f, sz = 0.f, sn = 0.f;
                RGRP(0) RGRP(1) RGRP(2) RGRP(3)
                RGRP(4) RGRP(5) RGRP(6) RGRP(7)
                const float r = sigmoid_fast(par + sr);
                const float z = sigmoid_fast(paz + sz);
                const float n = tanh_fast(pan + r * (bhnr + sn));
                h = n + z * (h - n);
                par = nar; paz = naz; pan = nan;
            }
        }

        // ---- tail: backward single cell step + FC ----
        float ar   = b_ih_b[j]          + b_hh_b[j];
        float az   = b_ih_b[Hh + j]     + b_hh_b[Hh + j];
        float axn  = b_ih_b[2 * Hh + j];
        const float bhnb = b_hh_b[2 * Hh + j];
        {
            const float4* xl = (const float4*)(xrow + (size_t)(Tt - 1) * Dd);
            float4 xv0 = xl[0], xv1 = xl[1], xv2 = xl[2], xv3 = xl[3];
            const float4* q0 = (const float4*)(w_ih_b + (size_t)j            * Dd);
            const float4* q1 = (const float4*)(w_ih_b + (size_t)(Hh + j)     * Dd);
            const float4* q2 = (const float4*)(w_ih_b + (size_t)(2 * Hh + j) * Dd);
            ar  += dot4(q0[0], xv0) + dot4(q0[1], xv1) + dot4(q0[2], xv2) + dot4(q0[3], xv3);
            az  += dot4(q1[0], xv0) + dot4(q1[1], xv1) + dot4(q1[2], xv2) + dot4(q1[3], xv3);
            axn += dot4(q2[0], xv0) + dot4(q2[1], xv1) + dot4(q2[2], xv2) + dot4(q2[3], xv3);
        }
        const float rb = sigmoid_fast(ar);
        const float zb = sigmoid_fast(az);
        const float nb = tanh_fast(axn + rb * bhnb);
        const float hb = (1.0f - zb) * nb;   // h0 = 0

        float v = fc_w[j] * h + fc_w[Hh + j] * hb;
#pragma unroll
        for (int off = 32; off > 0; off >>= 1)
            v += __shfl_xor(v, off, 64);
        if (j == 0) out[b] = v + fc_b[0];
    } else {
        // ================= PRODUCERS: input projections ====================
        const int pw = (w > cons) ? (w - 1) : w;   // 0..2
        float4 wir[4], wiz[4], win[4];
        {
            const float4* p0 = (const float4*)(w_ih_f + (size_t)j            * Dd);
            const float4* p1 = (const float4*)(w_ih_f + (size_t)(Hh + j)     * Dd);
            const float4* p2 = (const float4*)(w_ih_f + (size_t)(2 * Hh + j) * Dd);
#pragma unroll
            for (int q = 0; q < 4; ++q) { wir[q] = p0[q]; wiz[q] = p1[q]; win[q] = p2[q]; }
        }
        const float bxr = b_ih_f[j]          + b_hh_f[j];
        const float bxz = b_ih_f[Hh + j]     + b_hh_f[Hh + j];
        const float bxn = b_ih_f[2 * Hh + j];

#define PRODUCE(C1) {                                                        \
            float* obase = xgs + ((C1) & 1) * BUFSZ + j;                     \
            for (int tt = pw; tt < CH; tt += 3) {                            \
                const float4* xq = (const float4*)(xrow + (size_t)((C1) * CH + tt) * Dd); \
                float4 x0 = xq[0], x1 = xq[1], x2 = xq[2], x3 = xq[3];       \
                float ar_ = bxr + dot4(wir[0],x0) + dot4(wir[1],x1)          \
                                + dot4(wir[2],x2) + dot4(wir[3],x3);         \
                float az_ = bxz + dot4(wiz[0],x0) + dot4(wiz[1],x1)          \
                                + dot4(wiz[2],x2) + dot4(wiz[3],x3);         \
                float an_ = bxn + dot4(win[0],x0) + dot4(win[1],x1)          \
                                + dot4(win[2],x2) + dot4(win[3],x3);         \
                float* o = obase + tt * Hh;                                  \
                o[0] = ar_; o[PLANE] = az_; o[2 * PLANE] = an_;              \
            }                                                                \
        }

        PRODUCE(0);                       // chunk 0 before the first barrier
        for (int c = 0; c < NC; ++c) {
            lds_barrier();                // publish chunk c / consumer enters
            if (c + 1 < NC) PRODUCE(c + 1);  // fill other buffer during chunk c
        }
#undef PRODUCE
    }
}

extern "C" void kernel_launch(void* const* d_in, const int* in_sizes, int n_in,
                              void* d_out, int out_size, void* d_ws, size_t ws_size,
                              hipStream_t stream) {
    const float* x      = (const float*)d_in[0];
    const float* w_ih_f = (const float*)d_in[1];
    const float* w_hh_f = (const float*)d_in[2];
    const float* b_ih_f = (const float*)d_in[3];
    const float* b_hh_f = (const float*)d_in[4];
    const float* w_ih_b = (const float*)d_in[5];
    const float* w_hh_b = (const float*)d_in[6];
    const float* b_ih_b = (const float*)d_in[7];
    const float* b_hh_b = (const float*)d_in[8];
    const float* fc_w   = (const float*)d_in[9];
    const float* fc_b   = (const float*)d_in[10];

    bigru_pc_kernel<<<dim3(Bb), dim3(256), 0, stream>>>(
        x, w_ih_f, w_hh_f, b_ih_f, b_hh_f,
        w_ih_b, w_hh_b, b_ih_b, b_hh_b, fc_w, fc_b,
        (float*)d_out);
}

// Round 8
// 308.049 us; speedup vs baseline: 1.9585x; 1.1802x over previous
//
#include <hip/hip_runtime.h>

// BiGRU, B=512, T=512, D=16, H=64.
// Backward direction needs only ONE cell step (ys_b[0] = GRUCell(x[:,T-1,:], 0)).
//
// Round-10: producer/consumer (R7 structure, 304us) with the h-broadcast
// mechanism swapped: 64 v_readlane/step  ->  1 ds_write_b32 + 16 uniform
// ds_read_b128 (LDS broadcast).
//  Evidence: R4 (global-fed) and R7 (LDS-fed) both cost 1425 cyc/step --
//  the feed was never the chain cost. 64 readlanes @ ~8cyc (cross-lane +
//  VALU->SGPR->VALU hazard) + 192 FMA @2 + trans ~80 = ~1420 = measured.
//  LDS broadcast: 17 DS ops replace 64 readlanes; reads are pipelined and
//  wave-uniform (pure broadcast, conflict-free).
//  Also: 2-way split accumulators (6 chains), xg prefetch clamped in-array.

#define Hh 64
#define Dd 16
#define Tt 512
#define Bb 512
#define CH 32
#define NC (Tt / CH)        // 16 chunks
#define PLANE (CH * Hh)     // 2048 floats per gate plane
#define BUFSZ (3 * PLANE)   // 6144 floats per buffer

__device__ __forceinline__ float rcp_fast(float v) { return __builtin_amdgcn_rcpf(v); }
__device__ __forceinline__ float sigmoid_fast(float v) {
    return rcp_fast(1.0f + __expf(-v));
}
__device__ __forceinline__ float tanh_fast(float v) {
    return 1.0f - 2.0f * rcp_fast(__expf(2.0f * v) + 1.0f);
}
__device__ __forceinline__ float dot4(float4 a, float4 b) {
    return a.x * b.x + a.y * b.y + a.z * b.z + a.w * b.w;
}
// waitcnt + barrier: orders LDS ops across waves; both branches execute
// exactly NC barriers (wave-uniform branch).
__device__ __forceinline__ void lds_barrier() {
    asm volatile("s_waitcnt lgkmcnt(0)\n\ts_barrier" ::: "memory");
}

// 12 FMAs from one broadcast quad Q covering k = K..K+3; 2-way split chains.
#define QF(Q, K)                                                             \
    sr0 += whr[(K)+0]*Q.x; sz0 += whz[(K)+0]*Q.x; sn0 += whn[(K)+0]*Q.x;     \
    sr1 += whr[(K)+1]*Q.y; sz1 += whz[(K)+1]*Q.y; sn1 += whn[(K)+1]*Q.y;     \
    sr0 += whr[(K)+2]*Q.z; sz0 += whz[(K)+2]*Q.z; sn0 += whn[(K)+2]*Q.z;     \
    sr1 += whr[(K)+3]*Q.w; sz1 += whz[(K)+3]*Q.w; sn1 += whn[(K)+3]*Q.w;

__global__ __launch_bounds__(256, 2)
void bigru_pc_kernel(const float* __restrict__ x,
                     const float* __restrict__ w_ih_f, const float* __restrict__ w_hh_f,
                     const float* __restrict__ b_ih_f, const float* __restrict__ b_hh_f,
                     const float* __restrict__ w_ih_b, const float* __restrict__ w_hh_b,
                     const float* __restrict__ b_ih_b, const float* __restrict__ b_hh_b,
                     const float* __restrict__ fc_w,  const float* __restrict__ fc_b,
                     float* __restrict__ out)
{
    const int tid  = threadIdx.x;
    const int j    = tid & 63;          // hidden unit
    const int w    = tid >> 6;          // wave 0..3
    const int b    = blockIdx.x;        // batch element
    const int cons = b & 3;             // consumer wave id (spread across SIMDs)

    __shared__ __align__(16) float xgs[2 * BUFSZ];   // 48 KB double-buffered xg
    __shared__ __align__(16) float hbuf[Hh];         // 256 B h broadcast buffer

    const float* xrow = x + (size_t)b * Tt * Dd;

    if (w == cons) {
        // ===================== CONSUMER: the recurrence =====================
        // Full W_hh rows {j,64+j,128+j}: 192 VGPRs. W_ih never live here.
        float whr[Hh], whz[Hh], whn[Hh];
        {
            const float4* r0 = (const float4*)(w_hh_f + (size_t)j            * Hh);
            const float4* r1 = (const float4*)(w_hh_f + (size_t)(Hh + j)     * Hh);
            const float4* r2 = (const float4*)(w_hh_f + (size_t)(2 * Hh + j) * Hh);
#pragma unroll
            for (int q = 0; q < Hh / 4; ++q) {
                float4 a = r0[q]; whr[4*q] = a.x; whr[4*q+1] = a.y; whr[4*q+2] = a.z; whr[4*q+3] = a.w;
                float4 c = r1[q]; whz[4*q] = c.x; whz[4*q+1] = c.y; whz[4*q+2] = c.z; whz[4*q+3] = c.w;
                float4 e = r2[q]; whn[4*q] = e.x; whn[4*q+1] = e.y; whn[4*q+2] = e.z; whn[4*q+3] = e.w;
            }
        }
        const float bhnr = b_hh_f[2 * Hh + j];
        float h = 0.0f;

        for (int c = 0; c < NC; ++c) {
            lds_barrier();                       // chunk c ready in buf[c&1]
            const float* base = xgs + (c & 1) * BUFSZ + j;
            float par = base[0];
            float paz = base[PLANE];
            float pan = base[2 * PLANE];
#pragma unroll 2
            for (int t = 0; t < CH; ++t) {
                hbuf[j] = h;                     // publish h (in-order DS pipe)
                // prefetch next step's xg (clamped in-array; dead at t=CH-1)
                const int tn = (t + 1) & (CH - 1);
                const float* p = base + tn * Hh;
                const float nar = p[0];
                const float naz = p[PLANE];
                const float nan = p[2 * PLANE];

                const float4* hq = (const float4*)hbuf;   // wave-uniform addr
                float sr0 = 0.f, sr1 = 0.f, sz0 = 0.f, sz1 = 0.f, sn0 = 0.f, sn1 = 0.f;
                float4 q0 = hq[0],  q1 = hq[1],  q2 = hq[2],  q3 = hq[3];
                float4 q4 = hq[4],  q5 = hq[5],  q6 = hq[6],  q7 = hq[7];
                QF(q0, 0)  QF(q1, 4)  QF(q2, 8)  QF(q3, 12)
                q0 = hq[8];  q1 = hq[9];  q2 = hq[10]; q3 = hq[11];
                QF(q4, 16) QF(q5, 20) QF(q6, 24) QF(q7, 28)
                q4 = hq[12]; q5 = hq[13]; q6 = hq[14]; q7 = hq[15];
                QF(q0, 32) QF(q1, 36) QF(q2, 40) QF(q3, 44)
                QF(q4, 48) QF(q5, 52) QF(q6, 56) QF(q7, 60)

                const float r = sigmoid_fast(par + (sr0 + sr1));
                const float z = sigmoid_fast(paz + (sz0 + sz1));
                const float n = tanh_fast(pan + r * (bhnr + (sn0 + sn1)));
                h = n + z * (h - n);
                par = nar; paz = naz; pan = nan;
            }
        }

        // ---- tail: backward single cell step + FC ----
        float ar   = b_ih_b[j]          + b_hh_b[j];
        float az   = b_ih_b[Hh + j]     + b_hh_b[Hh + j];
        float axn  = b_ih_b[2 * Hh + j];
        const float bhnb = b_hh_b[2 * Hh + j];
        {
            const float4* xl = (const float4*)(xrow + (size_t)(Tt - 1) * Dd);
            float4 xv0 = xl[0], xv1 = xl[1], xv2 = xl[2], xv3 = xl[3];
            const float4* q0 = (const float4*)(w_ih_b + (size_t)j            * Dd);
            const float4* q1 = (const float4*)(w_ih_b + (size_t)(Hh + j)     * Dd);
            const float4* q2 = (const float4*)(w_ih_b + (size_t)(2 * Hh + j) * Dd);
            ar  += dot4(q0[0], xv0) + dot4(q0[1], xv1) + dot4(q0[2], xv2) + dot4(q0[3], xv3);
            az  += dot4(q1[0], xv0) + dot4(q1[1], xv1) + dot4(q1[2], xv2) + dot4(q1[3], xv3);
            axn += dot4(q2[0], xv0) + dot4(q2[1], xv1) + dot4(q2[2], xv2) + dot4(q2[3], xv3);
        }
        const float rb = sigmoid_fast(ar);
        const float zb = sigmoid_fast(az);
        const float nb = tanh_fast(axn + rb * bhnb);
        const float hb = (1.0f - zb) * nb;   // h0 = 0

        float v = fc_w[j] * h + fc_w[Hh + j] * hb;
#pragma unroll
        for (int off = 32; off > 0; off >>= 1)
            v += __shfl_xor(v, off, 64);
        if (j == 0) out[b] = v + fc_b[0];
    } else {
        // ================= PRODUCERS: input projections ====================
        const int pw = (w > cons) ? (w - 1) : w;   // 0..2
        float4 wir[4], wiz[4], win[4];
        {
            const float4* p0 = (const float4*)(w_ih_f + (size_t)j            * Dd);
            const float4* p1 = (const float4*)(w_ih_f + (size_t)(Hh + j)     * Dd);
            const float4* p2 = (const float4*)(w_ih_f + (size_t)(2 * Hh + j) * Dd);
#pragma unroll
            for (int q = 0; q < 4; ++q) { wir[q] = p0[q]; wiz[q] = p1[q]; win[q] = p2[q]; }
        }
        const float bxr = b_ih_f[j]          + b_hh_f[j];
        const float bxz = b_ih_f[Hh + j]     + b_hh_f[Hh + j];
        const float bxn = b_ih_f[2 * Hh + j];

#define PRODUCE(C1) {                                                        \
            float* obase = xgs + ((C1) & 1) * BUFSZ + j;                     \
            for (int tt = pw; tt < CH; tt += 3) {                            \
                const float4* xq = (const float4*)(xrow + (size_t)((C1) * CH + tt) * Dd); \
                float4 x0 = xq[0], x1 = xq[1], x2 = xq[2], x3 = xq[3];       \
                float ar_ = bxr + dot4(wir[0],x0) + dot4(wir[1],x1)          \
                                + dot4(wir[2],x2) + dot4(wir[3],x3);         \
                float az_ = bxz + dot4(wiz[0],x0) + dot4(wiz[1],x1)          \
                                + dot4(wiz[2],x2) + dot4(wiz[3],x3);         \
                float an_ = bxn + dot4(win[0],x0) + dot4(win[1],x1)          \
                                + dot4(win[2],x2) + dot4(win[3],x3);         \
                float* o = obase + tt * Hh;                                  \
                o[0] = ar_; o[PLANE] = az_; o[2 * PLANE] = an_;              \
            }                                                                \
        }

        PRODUCE(0);                       // chunk 0 before the first barrier
        for (int c = 0; c < NC; ++c) {
            lds_barrier();                // publish chunk c / consumer enters
            if (c + 1 < NC) PRODUCE(c + 1);  // fill other buffer during chunk c
        }
#undef PRODUCE
    }
}

extern "C" void kernel_launch(void* const* d_in, const int* in_sizes, int n_in,
                              void* d_out, int out_size, void* d_ws, size_t ws_size,
                              hipStream_t stream) {
    const float* x      = (const float*)d_in[0];
    const float* w_ih_f = (const float*)d_in[1];
    const float* w_hh_f = (const float*)d_in[2];
    const float* b_ih_f = (const float*)d_in[3];
    const float* b_hh_f = (const float*)d_in[4];
    const float* w_ih_b = (const float*)d_in[5];
    const float* w_hh_b = (const float*)d_in[6];
    const float* b_ih_b = (const float*)d_in[7];
    const float* b_hh_b = (const float*)d_in[8];
    const float* fc_w   = (const float*)d_in[9];
    const float* fc_b   = (const float*)d_in[10];

    bigru_pc_kernel<<<dim3(Bb), dim3(256), 0, stream>>>(
        x, w_ih_f, w_hh_f, b_ih_f, b_hh_f,
        w_ih_b, w_hh_b, b_ih_b, b_hh_b, fc_w, fc_b,
        (float*)d_out);
}

// Round 9
// 287.172 us; speedup vs baseline: 2.1008x; 1.0727x over previous
//
#include <hip/hip_runtime.h>

// BiGRU, B=512, T=512, D=16, H=64.
// Backward direction needs only ONE cell step (ys_b[0] = GRUCell(x[:,T-1,:], 0)).
//
// Round-11: R8 producer/consumer shell (251us) + packed-FP32 matvec.
//  Evidence: consumer-SIMD issue ~860 cyc/step vs ~470 from source => issued-
//  instruction density is the lever (suspect AGPR operand copies for the 192
//  weight floats; VGPR_Count=120 < live floats in every such kernel).
//  Change: 192 v_fmac_f32 -> 96 v_pk_fma_f32 (VOP3P packed). Weights stored
//  as float2 pairs; h broadcast float4 quads split into lo/hi pairs for free.
//  Worst case pk is half-rate => neutral; full-rate => -192 issue cyc/step.
//  Broadcast reads issued before xg prefetch (RAW starts earlier).

#define Hh 64
#define Dd 16
#define Tt 512
#define Bb 512
#define CH 32
#define NC (Tt / CH)        // 16 chunks
#define PLANE (CH * Hh)     // 2048 floats per gate plane
#define BUFSZ (3 * PLANE)   // 6144 floats per buffer

typedef float v2f __attribute__((ext_vector_type(2)));

__device__ __forceinline__ float rcp_fast(float v) { return __builtin_amdgcn_rcpf(v); }
__device__ __forceinline__ float sigmoid_fast(float v) {
    return rcp_fast(1.0f + __expf(-v));
}
__device__ __forceinline__ float tanh_fast(float v) {
    return 1.0f - 2.0f * rcp_fast(__expf(2.0f * v) + 1.0f);
}
__device__ __forceinline__ float dot4(float4 a, float4 b) {
    return a.x * b.x + a.y * b.y + a.z * b.z + a.w * b.w;
}
// packed fp32 FMA: a = b*c + a  (elementwise on the 2-vector)
__device__ __forceinline__ void pkfma(v2f& a, v2f b, v2f c) {
    asm("v_pk_fma_f32 %0, %1, %2, %0" : "+v"(a) : "v"(b), "v"(c));
}
// waitcnt + barrier: orders LDS ops across waves; both branches execute
// exactly NC barriers (wave-uniform branch).
__device__ __forceinline__ void lds_barrier() {
    asm volatile("s_waitcnt lgkmcnt(0)\n\ts_barrier" ::: "memory");
}

// 6 packed FMAs from one broadcast quad Q covering k = 4*QI .. 4*QI+3.
// Pair index P = 2*QI. Accs: chain0 takes lo pair, chain1 takes hi pair.
#define QPK(Q, QI)                                                           \
    {                                                                        \
        const v2f lo_ = { Q.x, Q.y };                                        \
        const v2f hi_ = { Q.z, Q.w };                                        \
        pkfma(ar0, wr2[2*(QI)],     lo_);                                    \
        pkfma(az0, wz2[2*(QI)],     lo_);                                    \
        pkfma(an0, wn2[2*(QI)],     lo_);                                    \
        pkfma(ar1, wr2[2*(QI) + 1], hi_);                                    \
        pkfma(az1, wz2[2*(QI) + 1], hi_);                                    \
        pkfma(an1, wn2[2*(QI) + 1], hi_);                                    \
    }

__global__ __launch_bounds__(256, 2)
void bigru_pc_kernel(const float* __restrict__ x,
                     const float* __restrict__ w_ih_f, const float* __restrict__ w_hh_f,
                     const float* __restrict__ b_ih_f, const float* __restrict__ b_hh_f,
                     const float* __restrict__ w_ih_b, const float* __restrict__ w_hh_b,
                     const float* __restrict__ b_ih_b, const float* __restrict__ b_hh_b,
                     const float* __restrict__ fc_w,  const float* __restrict__ fc_b,
                     float* __restrict__ out)
{
    const int tid  = threadIdx.x;
    const int j    = tid & 63;          // hidden unit
    const int w    = tid >> 6;          // wave 0..3
    const int b    = blockIdx.x;        // batch element
    const int cons = b & 3;             // consumer wave id (spread across SIMDs)

    __shared__ __align__(16) float xgs[2 * BUFSZ];   // 48 KB double-buffered xg
    __shared__ __align__(16) float hbuf[Hh];         // 256 B h broadcast buffer

    const float* xrow = x + (size_t)b * Tt * Dd;

    if (w == cons) {
        // ===================== CONSUMER: the recurrence =====================
        // W_hh rows {j,64+j,128+j} as 3x32 float2 pairs (192 floats).
        v2f wr2[Hh/2], wz2[Hh/2], wn2[Hh/2];
        {
            const float4* r0 = (const float4*)(w_hh_f + (size_t)j            * Hh);
            const float4* r1 = (const float4*)(w_hh_f + (size_t)(Hh + j)     * Hh);
            const float4* r2 = (const float4*)(w_hh_f + (size_t)(2 * Hh + j) * Hh);
#pragma unroll
            for (int q = 0; q < Hh / 4; ++q) {
                float4 a = r0[q]; wr2[2*q] = (v2f){a.x, a.y}; wr2[2*q+1] = (v2f){a.z, a.w};
                float4 c = r1[q]; wz2[2*q] = (v2f){c.x, c.y}; wz2[2*q+1] = (v2f){c.z, c.w};
                float4 e = r2[q]; wn2[2*q] = (v2f){e.x, e.y}; wn2[2*q+1] = (v2f){e.z, e.w};
            }
        }
        const float bhnr = b_hh_f[2 * Hh + j];
        float h = 0.0f;

        for (int c = 0; c < NC; ++c) {
            lds_barrier();                       // chunk c ready in buf[c&1]
            const float* base = xgs + (c & 1) * BUFSZ + j;
            float par = base[0];
            float paz = base[PLANE];
            float pan = base[2 * PLANE];
#pragma unroll 2
            for (int t = 0; t < CH; ++t) {
                hbuf[j] = h;                     // publish h (in-order DS pipe)
                const float4* hq = (const float4*)hbuf;   // wave-uniform addr
                // issue broadcast reads FIRST (RAW latency starts now)
                float4 q0 = hq[0],  q1 = hq[1],  q2 = hq[2],  q3 = hq[3];
                float4 q4 = hq[4],  q5 = hq[5],  q6 = hq[6],  q7 = hq[7];
                // prefetch next step's xg (clamped in-array; dead at t=CH-1)
                const int tn = (t + 1) & (CH - 1);
                const float* p = base + tn * Hh;
                const float nar = p[0];
                const float naz = p[PLANE];
                const float nan = p[2 * PLANE];

                v2f ar0 = {0.f, 0.f}, ar1 = {0.f, 0.f};
                v2f az0 = {0.f, 0.f}, az1 = {0.f, 0.f};
                v2f an0 = {0.f, 0.f}, an1 = {0.f, 0.f};

                QPK(q0, 0)  QPK(q1, 1)  QPK(q2, 2)  QPK(q3, 3)
                q0 = hq[8];  q1 = hq[9];  q2 = hq[10]; q3 = hq[11];
                QPK(q4, 4)  QPK(q5, 5)  QPK(q6, 6)  QPK(q7, 7)
                q4 = hq[12]; q5 = hq[13]; q6 = hq[14]; q7 = hq[15];
                QPK(q0, 8)  QPK(q1, 9)  QPK(q2, 10) QPK(q3, 11)
                QPK(q4, 12) QPK(q5, 13) QPK(q6, 14) QPK(q7, 15)

                const float sr = (ar0.x + ar0.y) + (ar1.x + ar1.y);
                const float sz = (az0.x + az0.y) + (az1.x + az1.y);
                const float sn = (an0.x + an0.y) + (an1.x + an1.y);

                const float r = sigmoid_fast(par + sr);
                const float z = sigmoid_fast(paz + sz);
                const float n = tanh_fast(pan + r * (bhnr + sn));
                h = n + z * (h - n);
                par = nar; paz = naz; pan = nan;
            }
        }

        // ---- tail: backward single cell step + FC ----
        float ar   = b_ih_b[j]          + b_hh_b[j];
        float az   = b_ih_b[Hh + j]     + b_hh_b[Hh + j];
        float axn  = b_ih_b[2 * Hh + j];
        const float bhnb = b_hh_b[2 * Hh + j];
        {
            const float4* xl = (const float4*)(xrow + (size_t)(Tt - 1) * Dd);
            float4 xv0 = xl[0], xv1 = xl[1], xv2 = xl[2], xv3 = xl[3];
            const float4* q0 = (const float4*)(w_ih_b + (size_t)j            * Dd);
            const float4* q1 = (const float4*)(w_ih_b + (size_t)(Hh + j)     * Dd);
            const float4* q2 = (const float4*)(w_ih_b + (size_t)(2 * Hh + j) * Dd);
            ar  += dot4(q0[0], xv0) + dot4(q0[1], xv1) + dot4(q0[2], xv2) + dot4(q0[3], xv3);
            az  += dot4(q1[0], xv0) + dot4(q1[1], xv1) + dot4(q1[2], xv2) + dot4(q1[3], xv3);
            axn += dot4(q2[0], xv0) + dot4(q2[1], xv1) + dot4(q2[2], xv2) + dot4(q2[3], xv3);
        }
        const float rb = sigmoid_fast(ar);
        const float zb = sigmoid_fast(az);
        const float nb = tanh_fast(axn + rb * bhnb);
        const float hb = (1.0f - zb) * nb;   // h0 = 0

        float v = fc_w[j] * h + fc_w[Hh + j] * hb;
#pragma unroll
        for (int off = 32; off > 0; off >>= 1)
            v += __shfl_xor(v, off, 64);
        if (j == 0) out[b] = v + fc_b[0];
    } else {
        // ================= PRODUCERS: input projections ====================
        const int pw = (w > cons) ? (w - 1) : w;   // 0..2
        float4 wir[4], wiz[4], win[4];
        {
            const float4* p0 = (const float4*)(w_ih_f + (size_t)j            * Dd);
            const float4* p1 = (const float4*)(w_ih_f + (size_t)(Hh + j)     * Dd);
            const float4* p2 = (const float4*)(w_ih_f + (size_t)(2 * Hh + j) * Dd);
#pragma unroll
            for (int q = 0; q < 4; ++q) { wir[q] = p0[q]; wiz[q] = p1[q]; win[q] = p2[q]; }
        }
        const float bxr = b_ih_f[j]          + b_hh_f[j];
        const float bxz = b_ih_f[Hh + j]     + b_hh_f[Hh + j];
        const float bxn = b_ih_f[2 * Hh + j];

#define PRODUCE(C1) {                                                        \
            float* obase = xgs + ((C1) & 1) * BUFSZ + j;                     \
            for (int tt = pw; tt < CH; tt += 3) {                            \
                const float4* xq = (const float4*)(xrow + (size_t)((C1) * CH + tt) * Dd); \
                float4 x0 = xq[0], x1 = xq[1], x2 = xq[2], x3 = xq[3];       \
                float ar_ = bxr + dot4(wir[0],x0) + dot4(wir[1],x1)          \
                                + dot4(wir[2],x2) + dot4(wir[3],x3);         \
                float az_ = bxz + dot4(wiz[0],x0) + dot4(wiz[1],x1)          \
                                + dot4(wiz[2],x2) + dot4(wiz[3],x3);         \
                float an_ = bxn + dot4(win[0],x0) + dot4(win[1],x1)          \
                                + dot4(win[2],x2) + dot4(win[3],x3);         \
                float* o = obase + tt * Hh;                                  \
                o[0] = ar_; o[PLANE] = az_; o[2 * PLANE] = an_;              \
            }                                                                \
        }

        PRODUCE(0);                       // chunk 0 before the first barrier
        for (int c = 0; c < NC; ++c) {
            lds_barrier();                // publish chunk c / consumer enters
            if (c + 1 < NC) PRODUCE(c + 1);  // fill other buffer during chunk c
        }
#undef PRODUCE
    }
}

extern "C" void kernel_launch(void* const* d_in, const int* in_sizes, int n_in,
                              void* d_out, int out_size, void* d_ws, size_t ws_size,
                              hipStream_t stream) {
    const float* x      = (const float*)d_in[0];
    const float* w_ih_f = (const float*)d_in[1];
    const float* w_hh_f = (const float*)d_in[2];
    const float* b_ih_f = (const float*)d_in[3];
    const float* b_hh_f = (const float*)d_in[4];
    const float* w_ih_b = (const float*)d_in[5];
    const float* w_hh_b = (const float*)d_in[6];
    const float* b_ih_b = (const float*)d_in[7];
    const float* b_hh_b = (const float*)d_in[8];
    const float* fc_w   = (const float*)d_in[9];
    const float* fc_b   = (const float*)d_in[10];

    bigru_pc_kernel<<<dim3(Bb), dim3(256), 0, stream>>>(
        x, w_ih_f, w_hh_f, b_ih_f, b_hh_f,
        w_ih_b, w_hh_b, b_ih_b, b_hh_b, fc_w, fc_b,
        (float*)d_out);
}